// Round 1
// baseline (6554.015 us; speedup 1.0000x reference)
//
#include <hip/hip_runtime.h>

typedef short short8 __attribute__((ext_vector_type(8)));
typedef float f32x4 __attribute__((ext_vector_type(4)));

union V16 { uint4 u; unsigned short s[8]; short8 v; };

__device__ __forceinline__ unsigned short f2bf(float f) {
  unsigned u = __builtin_bit_cast(unsigned, f);
  u += 0x7fffu + ((u >> 16) & 1u);
  return (unsigned short)(u >> 16);
}
__device__ __forceinline__ float bf2f(unsigned short b) {
  unsigned u = ((unsigned)b) << 16;
  return __builtin_bit_cast(float, u);
}

// ---------------- weight transpose + bf16 cast: w[b][K][128] -> wT[b][128][K]
__global__ void tcast_kernel(const float* __restrict__ w, unsigned short* __restrict__ wT,
                             int K, int total) {
  int t = blockIdx.x * blockDim.x + threadIdx.x;
  if (t >= total) return;
  int b = t / (K * 128);
  int rem = t - b * K * 128;
  int r = rem / 128;
  int c = rem - r * 128;
  wT[(size_t)b * 128 * K + (size_t)c * K + r] = f2bf(w[t]);
}

// ---------------- edge-index dtype detector: int64 => all odd int32 words are 0
__global__ void detect_kernel(const int* __restrict__ ei, int samples, int* __restrict__ flag) {
  int t = blockIdx.x * blockDim.x + threadIdx.x;
  if (t < samples && (t & 1) && ei[t] != 0) atomicOr(flag, 1);  // 1 => int32 layout
}

// ---------------- in-degree counts (float)
__global__ void count_kernel(const int* __restrict__ ei, const int* __restrict__ flag,
                             float* __restrict__ cnt, int E) {
  int e = blockIdx.x * blockDim.x + threadIdx.x;
  if (e >= E) return;
  int f = *flag;
  size_t pos = (size_t)E + e;           // tgt row
  int t = f ? ei[pos] : ei[pos * 2];    // int64: low word
  unsafeAtomicAdd(&cnt[t], 1.0f);
}

// ---------------- fused MLP: z = LN(SiLU(relu(X@W0+b0)@W1+b1))
// 64 rows per block, 4 waves, MFMA 16x16x32 bf16.
template <int K, bool OUTBF>
__global__ __launch_bounds__(256) void mlp_kernel(
    const float* __restrict__ in, const unsigned short* __restrict__ w0T,
    const float* __restrict__ b0, const unsigned short* __restrict__ w1T,
    const float* __restrict__ b1, float* __restrict__ outF,
    unsigned short* __restrict__ outB, int N) {
  __shared__ unsigned short xs[64 * 128];   // X tile (64 x K), later T (64 x 128)
  __shared__ unsigned short wl[128 * 128];  // W0T (128 x K), later W1T (128 x 128)
  const int tid = threadIdx.x;
  const int lane = tid & 63;
  const int wv = tid >> 6;
  const int row0 = blockIdx.x * 64;

  // ---- stage X -> xs (f32->bf16, XOR-swizzled rows), W0T -> wl
  {
    constexpr int CPR = K / 8;  // 16B chunks per row
    for (int c = tid; c < 64 * CPR; c += 256) {
      int r = c / CPR;
      int kc = (c % CPR) * 8;
      int g = row0 + r;
      V16 o;
      if (g < N) {
        const float4* p = (const float4*)(in + (size_t)g * K + kc);
        float4 v0 = p[0], v1 = p[1];
        o.s[0] = f2bf(v0.x); o.s[1] = f2bf(v0.y); o.s[2] = f2bf(v0.z); o.s[3] = f2bf(v0.w);
        o.s[4] = f2bf(v1.x); o.s[5] = f2bf(v1.y); o.s[6] = f2bf(v1.z); o.s[7] = f2bf(v1.w);
      } else {
        o.u.x = 0; o.u.y = 0; o.u.z = 0; o.u.w = 0;
      }
      unsigned byte = ((unsigned)(r * K + kc) * 2u) ^ ((unsigned)(r & 7) << 4);
      *(uint4*)((char*)xs + byte) = o.u;
    }
    for (int c = tid; c < 128 * CPR; c += 256) {
      int n = c / CPR;
      int kc = (c % CPR) * 8;
      uint4 v = *(const uint4*)(w0T + (size_t)n * K + kc);
      unsigned byte = ((unsigned)(n * K + kc) * 2u) ^ ((unsigned)(n & 7) << 4);
      *(uint4*)((char*)wl + byte) = v;
    }
  }
  __syncthreads();

  // ---- stage 1: T = X @ W0   (per wave: 16 rows x 128 cols)
  short8 afr[K / 32];
  {
    int r = wv * 16 + (lane & 15);
    int kb = (lane >> 4) * 8;
#pragma unroll
    for (int k0 = 0; k0 < K / 32; k0++) {
      unsigned byte = ((unsigned)(r * K + k0 * 32 + kb) * 2u) ^ ((unsigned)(r & 7) << 4);
      afr[k0] = *(const short8*)((char*)xs + byte);
    }
  }
  f32x4 acc[8];
#pragma unroll
  for (int n0 = 0; n0 < 8; n0++) acc[n0] = (f32x4){0.f, 0.f, 0.f, 0.f};
  {
    int cb = lane & 15;
    int kb = (lane >> 4) * 8;
#pragma unroll
    for (int n0 = 0; n0 < 8; n0++) {
      int n = n0 * 16 + cb;
#pragma unroll
      for (int k0 = 0; k0 < K / 32; k0++) {
        unsigned byte = ((unsigned)(n * K + k0 * 32 + kb) * 2u) ^ ((unsigned)(n & 7) << 4);
        short8 bfr = *(const short8*)((char*)wl + byte);
        acc[n0] = __builtin_amdgcn_mfma_f32_16x16x32_bf16(afr[k0], bfr, acc[n0], 0, 0, 0);
      }
    }
  }
  __syncthreads();

  // ---- T = relu(acc + b0) -> xs (bf16), stage W1T -> wl
  {
    int cb = lane & 15;
    int rr0 = wv * 16 + (lane >> 4) * 4;
#pragma unroll
    for (int n0 = 0; n0 < 8; n0++) {
      int col = n0 * 16 + cb;
      float bb = b0[col];
#pragma unroll
      for (int j = 0; j < 4; j++) {
        float v = acc[n0][j] + bb;
        v = v > 0.f ? v : 0.f;
        int rr = rr0 + j;
        unsigned byte = ((unsigned)(rr * 128 + col) * 2u) ^ ((unsigned)(rr & 7) << 4);
        *(unsigned short*)((char*)xs + byte) = f2bf(v);
      }
    }
    for (int c = tid; c < 128 * 16; c += 256) {
      int n = c >> 4;
      int kc = (c & 15) * 8;
      uint4 v = *(const uint4*)(w1T + (size_t)n * 128 + kc);
      unsigned byte = ((unsigned)(n * 128 + kc) * 2u) ^ ((unsigned)(n & 7) << 4);
      *(uint4*)((char*)wl + byte) = v;
    }
  }
  __syncthreads();

  // ---- stage 2: Z = T @ W1
  short8 a2[4];
  {
    int r = wv * 16 + (lane & 15);
    int kb = (lane >> 4) * 8;
#pragma unroll
    for (int k0 = 0; k0 < 4; k0++) {
      unsigned byte = ((unsigned)(r * 128 + k0 * 32 + kb) * 2u) ^ ((unsigned)(r & 7) << 4);
      a2[k0] = *(const short8*)((char*)xs + byte);
    }
  }
  f32x4 z[8];
#pragma unroll
  for (int n0 = 0; n0 < 8; n0++) z[n0] = (f32x4){0.f, 0.f, 0.f, 0.f};
  {
    int cb = lane & 15;
    int kb = (lane >> 4) * 8;
#pragma unroll
    for (int n0 = 0; n0 < 8; n0++) {
      int n = n0 * 16 + cb;
#pragma unroll
      for (int k0 = 0; k0 < 4; k0++) {
        unsigned byte = ((unsigned)(n * 128 + k0 * 32 + kb) * 2u) ^ ((unsigned)(n & 7) << 4);
        short8 bfr = *(const short8*)((char*)wl + byte);
        z[n0] = __builtin_amdgcn_mfma_f32_16x16x32_bf16(a2[k0], bfr, z[n0], 0, 0, 0);
      }
    }
  }

  // ---- epilogue: +b1, SiLU, LayerNorm over the 128-col row, store
  {
    int cb = lane & 15;
    float sum[4] = {0.f, 0.f, 0.f, 0.f}, sq[4] = {0.f, 0.f, 0.f, 0.f};
#pragma unroll
    for (int n0 = 0; n0 < 8; n0++) {
      float bb = b1[n0 * 16 + cb];
#pragma unroll
      for (int j = 0; j < 4; j++) {
        float v = z[n0][j] + bb;
        float sg = v / (1.f + __expf(-v));  // SiLU
        z[n0][j] = sg;
        sum[j] += sg;
        sq[j] += sg * sg;
      }
    }
#pragma unroll
    for (int m = 1; m <= 8; m <<= 1) {
#pragma unroll
      for (int j = 0; j < 4; j++) {
        sum[j] += __shfl_xor(sum[j], m, 64);
        sq[j] += __shfl_xor(sq[j], m, 64);
      }
    }
    int rr0 = wv * 16 + (lane >> 4) * 4;
#pragma unroll
    for (int j = 0; j < 4; j++) {
      int g = row0 + rr0 + j;
      if (g >= N) continue;
      float mu = sum[j] * (1.f / 128.f);
      float var = sq[j] * (1.f / 128.f) - mu * mu;
      float rs = rsqrtf(var + 1e-5f);
#pragma unroll
      for (int n0 = 0; n0 < 8; n0++) {
        float v = (z[n0][j] - mu) * rs;
        int col = n0 * 16 + cb;
        if (OUTBF) outB[(size_t)g * 128 + col] = f2bf(v);
        else outF[(size_t)g * 128 + col] = v;
      }
    }
  }
}

// ---------------- scatter: agg[tgt] += z[src]  (16 threads/edge, 8 cols each)
__global__ __launch_bounds__(256) void scatter_kernel(
    const unsigned short* __restrict__ z, const int* __restrict__ ei,
    const int* __restrict__ flag, float* __restrict__ agg, int E) {
  int t = blockIdx.x * 256 + threadIdx.x;
  int e = t >> 4;
  if (e >= E) return;
  int f = *flag;
  int s = f ? ei[e] : ei[(size_t)e * 2];
  int d = f ? ei[(size_t)E + e] : ei[((size_t)E + e) * 2];
  int c = (t & 15) * 8;
  V16 v;
  v.u = *(const uint4*)(z + (size_t)s * 128 + c);
  float* ap = agg + (size_t)d * 128 + c;
#pragma unroll
  for (int i = 0; i < 8; i++) unsafeAtomicAdd(ap + i, bf2f(v.s[i]));
}

// ---------------- h = agg/cnt + h  (in place in d_out)
__global__ __launch_bounds__(256) void residual_kernel(
    const float* __restrict__ agg, const float* __restrict__ cnt,
    float* __restrict__ h, int N) {
  int t = blockIdx.x * 256 + threadIdx.x;
  if (t >= N * 32) return;
  int i = t >> 5;
  int c = (t & 31) * 4;
  float cv = cnt[i];
  float inv = cv > 0.f ? 1.f / cv : 0.f;
  float4 a = *(const float4*)(agg + (size_t)i * 128 + c);
  float4 hv = *(const float4*)(h + (size_t)i * 128 + c);
  hv.x += a.x * inv; hv.y += a.y * inv; hv.z += a.z * inv; hv.w += a.w * inv;
  *(float4*)(h + (size_t)i * 128 + c) = hv;
}

extern "C" void kernel_launch(void* const* d_in, const int* in_sizes, int n_in,
                              void* d_out, int out_size, void* d_ws, size_t ws_size,
                              hipStream_t stream) {
  const float* x = (const float*)d_in[0];
  const int* ei = (const int*)d_in[1];
  const float* ie_w0 = (const float*)d_in[2];
  const float* ie_b0 = (const float*)d_in[3];
  const float* ie_w1 = (const float*)d_in[4];
  const float* ie_b1 = (const float*)d_in[5];
  const float* lw0 = (const float*)d_in[6];
  const float* lb0 = (const float*)d_in[7];
  const float* lw1 = (const float*)d_in[8];
  const float* lb1 = (const float*)d_in[9];
  const int N = in_sizes[0] / 64;
  const int E = in_sizes[1] / 2;
  float* h = (float*)d_out;

  char* ws = (char*)d_ws;
  size_t off = 0;
  auto carve = [&](size_t bytes) { void* p = ws + off; off = (off + bytes + 255) & ~(size_t)255; return p; };
  unsigned short* zbuf = (unsigned short*)carve((size_t)N * 128 * 2);
  float* agg = (float*)carve((size_t)N * 128 * 4);
  float* cnt = (float*)carve((size_t)N * 4);
  int* flag = (int*)carve(256);
  unsigned short* w0T_ie = (unsigned short*)carve(128 * 64 * 2);
  unsigned short* w1T_ie = (unsigned short*)carve(128 * 128 * 2);
  unsigned short* w0T_l = (unsigned short*)carve(3 * 128 * 128 * 2);
  unsigned short* w1T_l = (unsigned short*)carve(3 * 128 * 128 * 2);

  // dtype detect (int32 vs int64 edge_index), weight prep, counts
  hipMemsetAsync(flag, 0, 4, stream);
  int samples = 2 * E < 8192 ? 2 * E : 8192;
  detect_kernel<<<(samples + 255) / 256, 256, 0, stream>>>(ei, samples, flag);
  tcast_kernel<<<(64 * 128 + 255) / 256, 256, 0, stream>>>(ie_w0, w0T_ie, 64, 64 * 128);
  tcast_kernel<<<(128 * 128 + 255) / 256, 256, 0, stream>>>(ie_w1, w1T_ie, 128, 128 * 128);
  tcast_kernel<<<(3 * 128 * 128 + 255) / 256, 256, 0, stream>>>(lw0, w0T_l, 128, 3 * 128 * 128);
  tcast_kernel<<<(3 * 128 * 128 + 255) / 256, 256, 0, stream>>>(lw1, w1T_l, 128, 3 * 128 * 128);
  hipMemsetAsync(cnt, 0, (size_t)N * 4, stream);
  count_kernel<<<(E + 255) / 256, 256, 0, stream>>>(ei, flag, cnt, E);

  // initial embedding: h = LN(SiLU(relu(x@W0+b0)@W1+b1))
  mlp_kernel<64, false><<<(N + 63) / 64, 256, 0, stream>>>(
      x, w0T_ie, ie_b0, w1T_ie, ie_b1, h, nullptr, N);

  for (int l = 0; l < 3; l++) {
    mlp_kernel<128, true><<<(N + 63) / 64, 256, 0, stream>>>(
        h, w0T_l + (size_t)l * 128 * 128, lb0 + (size_t)l * 128,
        w1T_l + (size_t)l * 128 * 128, lb1 + (size_t)l * 128, nullptr, zbuf, N);
    hipMemsetAsync(agg, 0, (size_t)N * 128 * 4, stream);
    scatter_kernel<<<((size_t)E * 16 + 255) / 256, 256, 0, stream>>>(zbuf, ei, flag, agg, E);
    residual_kernel<<<((size_t)N * 32 + 255) / 256, 256, 0, stream>>>(agg, cnt, h, N);
  }
}

// Round 2
// 337.726 us; speedup vs baseline: 19.4063x; 19.4063x over previous
//
#include <hip/hip_runtime.h>

typedef short short8 __attribute__((ext_vector_type(8)));
typedef float f32x4 __attribute__((ext_vector_type(4)));

union V16 { uint4 u; unsigned short s[8]; short8 v; };

__device__ __forceinline__ unsigned short f2bf(float f) {
  unsigned u = __builtin_bit_cast(unsigned, f);
  u += 0x7fffu + ((u >> 16) & 1u);
  return (unsigned short)(u >> 16);
}
__device__ __forceinline__ float bf2f(unsigned short b) {
  unsigned u = ((unsigned)b) << 16;
  return __builtin_bit_cast(float, u);
}

// ---------------- weight transpose + bf16 cast: w[b][K][128] -> wT[b][128][K]
__global__ void tcast_kernel(const float* __restrict__ w, unsigned short* __restrict__ wT,
                             int K, int total) {
  int t = blockIdx.x * blockDim.x + threadIdx.x;
  if (t >= total) return;
  int b = t / (K * 128);
  int rem = t - b * K * 128;
  int r = rem / 128;
  int c = rem - r * 128;
  wT[(size_t)b * 128 * K + (size_t)c * K + r] = f2bf(w[t]);
}

// ---------------- edge-index dtype detector: int64 => all odd int32 words are 0
__global__ void detect_kernel(const int* __restrict__ ei, int samples, int* __restrict__ flag) {
  int t = blockIdx.x * blockDim.x + threadIdx.x;
  if (t < samples && (t & 1) && ei[t] != 0) atomicOr(flag, 1);  // 1 => int32 layout
}

// ---------------- in-degree counts (int)
__global__ void counti_kernel(const int* __restrict__ ei, const int* __restrict__ flag,
                              int* __restrict__ cnt, int E) {
  int e = blockIdx.x * blockDim.x + threadIdx.x;
  if (e >= E) return;
  int f = *flag;
  size_t pos = (size_t)E + e;           // tgt row
  int t = f ? ei[pos] : ei[pos * 2];    // int64: low word
  atomicAdd(&cnt[t], 1);
}

// ---------------- hierarchical exclusive scan (1024 elems / block)
__global__ __launch_bounds__(256) void scanA_kernel(const int* __restrict__ cnt,
                                                    int* __restrict__ bsums, int N) {
  int base = blockIdx.x * 1024 + threadIdx.x * 4;
  int s = 0;
#pragma unroll
  for (int j = 0; j < 4; j++) { int i = base + j; if (i < N) s += cnt[i]; }
#pragma unroll
  for (int m = 1; m < 64; m <<= 1) s += __shfl_xor(s, m, 64);
  __shared__ int ws[4];
  int lane = threadIdx.x & 63, wv = threadIdx.x >> 6;
  if (lane == 0) ws[wv] = s;
  __syncthreads();
  if (threadIdx.x == 0) bsums[blockIdx.x] = ws[0] + ws[1] + ws[2] + ws[3];
}

__global__ __launch_bounds__(256) void scanB_kernel(int* __restrict__ bsums, int NB) {
  int tid = threadIdx.x;
  int base = tid * 4;
  int v[4];
#pragma unroll
  for (int j = 0; j < 4; j++) v[j] = (base + j < NB) ? bsums[base + j] : 0;
  int s = v[0] + v[1] + v[2] + v[3];
  int lane = tid & 63, wv = tid >> 6;
  int ps = s;
#pragma unroll
  for (int d = 1; d < 64; d <<= 1) { int o = __shfl_up(ps, d, 64); if (lane >= d) ps += o; }
  __shared__ int ws[4];
  if (lane == 63) ws[wv] = ps;
  __syncthreads();
  int woff = 0;
  for (int i = 0; i < wv; i++) woff += ws[i];
  int run = woff + ps - s;  // exclusive prefix
#pragma unroll
  for (int j = 0; j < 4; j++) {
    if (base + j < NB) { int t = bsums[base + j]; bsums[base + j] = run; run += t; }
  }
}

__global__ __launch_bounds__(256) void scanC_kernel(const int* __restrict__ cnt,
                                                    const int* __restrict__ bsums,
                                                    int* __restrict__ off, int N) {
  int base = blockIdx.x * 1024 + threadIdx.x * 4;
  int v[4];
#pragma unroll
  for (int j = 0; j < 4; j++) v[j] = (base + j < N) ? cnt[base + j] : 0;
  int s = v[0] + v[1] + v[2] + v[3];
  int lane = threadIdx.x & 63, wv = threadIdx.x >> 6;
  int ps = s;
#pragma unroll
  for (int d = 1; d < 64; d <<= 1) { int o = __shfl_up(ps, d, 64); if (lane >= d) ps += o; }
  __shared__ int ws[4];
  if (lane == 63) ws[wv] = ps;
  __syncthreads();
  int woff = 0;
  for (int i = 0; i < wv; i++) woff += ws[i];
  int run = woff + ps - s + bsums[blockIdx.x];
#pragma unroll
  for (int j = 0; j < 4; j++) {
    if (base + j < N) { off[base + j] = run; run += v[j]; }
  }
}

// ---------------- CSR fill: elist[off[t] + cursor[t]++] = src
__global__ void fill_kernel(const int* __restrict__ ei, const int* __restrict__ flag,
                            const int* __restrict__ off, int* __restrict__ cursor,
                            int* __restrict__ elist, int E) {
  int e = blockIdx.x * blockDim.x + threadIdx.x;
  if (e >= E) return;
  int f = *flag;
  int s = f ? ei[e] : ei[(size_t)e * 2];
  int t = f ? ei[(size_t)E + e] : ei[((size_t)E + e) * 2];
  int p = off[t] + atomicAdd(&cursor[t], 1);
  elist[p] = s;
}

// ---------------- fused MLP: z = LN(SiLU(relu(X@W0+b0)@W1+b1))
// 64 rows per block, 4 waves, MFMA 16x16x32 bf16.
template <int K, bool OUTBF>
__global__ __launch_bounds__(256) void mlp_kernel(
    const float* __restrict__ in, const unsigned short* __restrict__ w0T,
    const float* __restrict__ b0, const unsigned short* __restrict__ w1T,
    const float* __restrict__ b1, float* __restrict__ outF,
    unsigned short* __restrict__ outB, int N) {
  __shared__ unsigned short xs[64 * 128];   // X tile (64 x K), later T (64 x 128)
  __shared__ unsigned short wl[128 * 128];  // W0T (128 x K), later W1T (128 x 128)
  const int tid = threadIdx.x;
  const int lane = tid & 63;
  const int wv = tid >> 6;
  const int row0 = blockIdx.x * 64;

  // ---- stage X -> xs (f32->bf16, XOR-swizzled rows), W0T -> wl
  {
    constexpr int CPR = K / 8;  // 16B chunks per row
    for (int c = tid; c < 64 * CPR; c += 256) {
      int r = c / CPR;
      int kc = (c % CPR) * 8;
      int g = row0 + r;
      V16 o;
      if (g < N) {
        const float4* p = (const float4*)(in + (size_t)g * K + kc);
        float4 v0 = p[0], v1 = p[1];
        o.s[0] = f2bf(v0.x); o.s[1] = f2bf(v0.y); o.s[2] = f2bf(v0.z); o.s[3] = f2bf(v0.w);
        o.s[4] = f2bf(v1.x); o.s[5] = f2bf(v1.y); o.s[6] = f2bf(v1.z); o.s[7] = f2bf(v1.w);
      } else {
        o.u.x = 0; o.u.y = 0; o.u.z = 0; o.u.w = 0;
      }
      unsigned byte = ((unsigned)(r * K + kc) * 2u) ^ ((unsigned)(r & 7) << 4);
      *(uint4*)((char*)xs + byte) = o.u;
    }
    for (int c = tid; c < 128 * CPR; c += 256) {
      int n = c / CPR;
      int kc = (c % CPR) * 8;
      uint4 v = *(const uint4*)(w0T + (size_t)n * K + kc);
      unsigned byte = ((unsigned)(n * K + kc) * 2u) ^ ((unsigned)(n & 7) << 4);
      *(uint4*)((char*)wl + byte) = v;
    }
  }
  __syncthreads();

  // ---- stage 1: T = X @ W0   (per wave: 16 rows x 128 cols)
  short8 afr[K / 32];
  {
    int r = wv * 16 + (lane & 15);
    int kb = (lane >> 4) * 8;
#pragma unroll
    for (int k0 = 0; k0 < K / 32; k0++) {
      unsigned byte = ((unsigned)(r * K + k0 * 32 + kb) * 2u) ^ ((unsigned)(r & 7) << 4);
      afr[k0] = *(const short8*)((char*)xs + byte);
    }
  }
  f32x4 acc[8];
#pragma unroll
  for (int n0 = 0; n0 < 8; n0++) acc[n0] = (f32x4){0.f, 0.f, 0.f, 0.f};
  {
    int cb = lane & 15;
    int kb = (lane >> 4) * 8;
#pragma unroll
    for (int n0 = 0; n0 < 8; n0++) {
      int n = n0 * 16 + cb;
#pragma unroll
      for (int k0 = 0; k0 < K / 32; k0++) {
        unsigned byte = ((unsigned)(n * K + k0 * 32 + kb) * 2u) ^ ((unsigned)(n & 7) << 4);
        short8 bfr = *(const short8*)((char*)wl + byte);
        acc[n0] = __builtin_amdgcn_mfma_f32_16x16x32_bf16(afr[k0], bfr, acc[n0], 0, 0, 0);
      }
    }
  }
  __syncthreads();

  // ---- T = relu(acc + b0) -> xs (bf16), stage W1T -> wl
  {
    int cb = lane & 15;
    int rr0 = wv * 16 + (lane >> 4) * 4;
#pragma unroll
    for (int n0 = 0; n0 < 8; n0++) {
      int col = n0 * 16 + cb;
      float bb = b0[col];
#pragma unroll
      for (int j = 0; j < 4; j++) {
        float v = acc[n0][j] + bb;
        v = v > 0.f ? v : 0.f;
        int rr = rr0 + j;
        unsigned byte = ((unsigned)(rr * 128 + col) * 2u) ^ ((unsigned)(rr & 7) << 4);
        *(unsigned short*)((char*)xs + byte) = f2bf(v);
      }
    }
    for (int c = tid; c < 128 * 16; c += 256) {
      int n = c >> 4;
      int kc = (c & 15) * 8;
      uint4 v = *(const uint4*)(w1T + (size_t)n * 128 + kc);
      unsigned byte = ((unsigned)(n * 128 + kc) * 2u) ^ ((unsigned)(n & 7) << 4);
      *(uint4*)((char*)wl + byte) = v;
    }
  }
  __syncthreads();

  // ---- stage 2: Z = T @ W1
  short8 a2[4];
  {
    int r = wv * 16 + (lane & 15);
    int kb = (lane >> 4) * 8;
#pragma unroll
    for (int k0 = 0; k0 < 4; k0++) {
      unsigned byte = ((unsigned)(r * 128 + k0 * 32 + kb) * 2u) ^ ((unsigned)(r & 7) << 4);
      a2[k0] = *(const short8*)((char*)xs + byte);
    }
  }
  f32x4 z[8];
#pragma unroll
  for (int n0 = 0; n0 < 8; n0++) z[n0] = (f32x4){0.f, 0.f, 0.f, 0.f};
  {
    int cb = lane & 15;
    int kb = (lane >> 4) * 8;
#pragma unroll
    for (int n0 = 0; n0 < 8; n0++) {
      int n = n0 * 16 + cb;
#pragma unroll
      for (int k0 = 0; k0 < 4; k0++) {
        unsigned byte = ((unsigned)(n * 128 + k0 * 32 + kb) * 2u) ^ ((unsigned)(n & 7) << 4);
        short8 bfr = *(const short8*)((char*)wl + byte);
        z[n0] = __builtin_amdgcn_mfma_f32_16x16x32_bf16(a2[k0], bfr, z[n0], 0, 0, 0);
      }
    }
  }

  // ---- epilogue: +b1, SiLU, LayerNorm over the 128-col row, store
  {
    int cb = lane & 15;
    float sum[4] = {0.f, 0.f, 0.f, 0.f}, sq[4] = {0.f, 0.f, 0.f, 0.f};
#pragma unroll
    for (int n0 = 0; n0 < 8; n0++) {
      float bb = b1[n0 * 16 + cb];
#pragma unroll
      for (int j = 0; j < 4; j++) {
        float v = z[n0][j] + bb;
        float sg = v / (1.f + __expf(-v));  // SiLU
        z[n0][j] = sg;
        sum[j] += sg;
        sq[j] += sg * sg;
      }
    }
#pragma unroll
    for (int m = 1; m <= 8; m <<= 1) {
#pragma unroll
      for (int j = 0; j < 4; j++) {
        sum[j] += __shfl_xor(sum[j], m, 64);
        sq[j] += __shfl_xor(sq[j], m, 64);
      }
    }
    int rr0 = wv * 16 + (lane >> 4) * 4;
#pragma unroll
    for (int j = 0; j < 4; j++) {
      int g = row0 + rr0 + j;
      if (g >= N) continue;
      float mu = sum[j] * (1.f / 128.f);
      float var = sq[j] * (1.f / 128.f) - mu * mu;
      float rs = rsqrtf(var + 1e-5f);
#pragma unroll
      for (int n0 = 0; n0 < 8; n0++) {
        float v = (z[n0][j] - mu) * rs;
        int col = n0 * 16 + cb;
        if (OUTBF) outB[(size_t)g * 128 + col] = f2bf(v);
        else outF[(size_t)g * 128 + col] = v;
      }
    }
  }
}

// ---------------- gather + residual: h[n] += mean_{e in CSR[n]} z[src[e]]
// 16 lanes per node, 8 cols each; z rows are contiguous 256B bf16.
__global__ __launch_bounds__(256) void gather_kernel(
    const unsigned short* __restrict__ z, const int* __restrict__ elist,
    const int* __restrict__ off, const int* __restrict__ cnt,
    float* __restrict__ h, int N) {
  int t = blockIdx.x * 256 + threadIdx.x;
  int g = t >> 4;
  if (g >= N) return;
  int c = (t & 15) * 8;
  int o = off[g];
  int n = cnt[g];
  float acc[8] = {0.f, 0.f, 0.f, 0.f, 0.f, 0.f, 0.f, 0.f};
  for (int i = 0; i < n; i++) {
    int s = elist[o + i];
    V16 v;
    v.u = *(const uint4*)(z + (size_t)s * 128 + c);
#pragma unroll
    for (int j = 0; j < 8; j++) acc[j] += bf2f(v.s[j]);
  }
  float inv = n > 0 ? 1.f / (float)n : 0.f;
  float* hp = h + (size_t)g * 128 + c;
  float4 h0 = *(const float4*)hp, h1 = *(const float4*)(hp + 4);
  h0.x += acc[0] * inv; h0.y += acc[1] * inv; h0.z += acc[2] * inv; h0.w += acc[3] * inv;
  h1.x += acc[4] * inv; h1.y += acc[5] * inv; h1.z += acc[6] * inv; h1.w += acc[7] * inv;
  *(float4*)hp = h0;
  *(float4*)(hp + 4) = h1;
}

extern "C" void kernel_launch(void* const* d_in, const int* in_sizes, int n_in,
                              void* d_out, int out_size, void* d_ws, size_t ws_size,
                              hipStream_t stream) {
  const float* x = (const float*)d_in[0];
  const int* ei = (const int*)d_in[1];
  const float* ie_w0 = (const float*)d_in[2];
  const float* ie_b0 = (const float*)d_in[3];
  const float* ie_w1 = (const float*)d_in[4];
  const float* ie_b1 = (const float*)d_in[5];
  const float* lw0 = (const float*)d_in[6];
  const float* lb0 = (const float*)d_in[7];
  const float* lw1 = (const float*)d_in[8];
  const float* lb1 = (const float*)d_in[9];
  const int N = in_sizes[0] / 64;
  const int E = in_sizes[1] / 2;
  float* h = (float*)d_out;

  char* ws = (char*)d_ws;
  size_t off_b = 0;
  auto carve = [&](size_t bytes) { void* p = ws + off_b; off_b = (off_b + bytes + 255) & ~(size_t)255; return p; };
  unsigned short* zbuf = (unsigned short*)carve((size_t)N * 128 * 2);
  int* elist = (int*)carve((size_t)E * 4);
  int* offs = (int*)carve((size_t)N * 4);
  int* cnti = (int*)carve((size_t)N * 4);
  int* cursor = (int*)carve((size_t)N * 4);
  int* bsums = (int*)carve(((size_t)(N + 1023) / 1024) * 4 + 256);
  int* flag = (int*)carve(256);
  unsigned short* w0T_ie = (unsigned short*)carve(128 * 64 * 2);
  unsigned short* w1T_ie = (unsigned short*)carve(128 * 128 * 2);
  unsigned short* w0T_l = (unsigned short*)carve(3 * 128 * 128 * 2);
  unsigned short* w1T_l = (unsigned short*)carve(3 * 128 * 128 * 2);

  const int NB = (N + 1023) / 1024;

  // dtype detect (int32 vs int64 edge_index), weight prep
  hipMemsetAsync(flag, 0, 4, stream);
  hipMemsetAsync(cnti, 0, (size_t)N * 4, stream);
  hipMemsetAsync(cursor, 0, (size_t)N * 4, stream);
  int samples = 2 * E < 8192 ? 2 * E : 8192;
  detect_kernel<<<(samples + 255) / 256, 256, 0, stream>>>(ei, samples, flag);
  tcast_kernel<<<(64 * 128 + 255) / 256, 256, 0, stream>>>(ie_w0, w0T_ie, 64, 64 * 128);
  tcast_kernel<<<(128 * 128 + 255) / 256, 256, 0, stream>>>(ie_w1, w1T_ie, 128, 128 * 128);
  tcast_kernel<<<(3 * 128 * 128 + 255) / 256, 256, 0, stream>>>(lw0, w0T_l, 128, 3 * 128 * 128);
  tcast_kernel<<<(3 * 128 * 128 + 255) / 256, 256, 0, stream>>>(lw1, w1T_l, 128, 3 * 128 * 128);

  // CSR build: counts -> exclusive scan -> bucket fill
  counti_kernel<<<(E + 255) / 256, 256, 0, stream>>>(ei, flag, cnti, E);
  scanA_kernel<<<NB, 256, 0, stream>>>(cnti, bsums, N);
  scanB_kernel<<<1, 256, 0, stream>>>(bsums, NB);
  scanC_kernel<<<NB, 256, 0, stream>>>(cnti, bsums, offs, N);
  fill_kernel<<<(E + 255) / 256, 256, 0, stream>>>(ei, flag, offs, cursor, elist, E);

  // initial embedding: h = LN(SiLU(relu(x@W0+b0)@W1+b1))
  mlp_kernel<64, false><<<(N + 63) / 64, 256, 0, stream>>>(
      x, w0T_ie, ie_b0, w1T_ie, ie_b1, h, nullptr, N);

  for (int l = 0; l < 3; l++) {
    mlp_kernel<128, true><<<(N + 63) / 64, 256, 0, stream>>>(
        h, w0T_l + (size_t)l * 128 * 128, lb0 + (size_t)l * 128,
        w1T_l + (size_t)l * 128 * 128, lb1 + (size_t)l * 128, nullptr, zbuf, N);
    gather_kernel<<<((size_t)N * 16 + 255) / 256, 256, 0, stream>>>(
        zbuf, elist, offs, cnti, h, N);
  }
}

// Round 3
// 330.897 us; speedup vs baseline: 19.8068x; 1.0206x over previous
//
#include <hip/hip_runtime.h>

typedef short short8 __attribute__((ext_vector_type(8)));
typedef float f32x4 __attribute__((ext_vector_type(4)));

union V16 { uint4 u; unsigned short s[8]; short8 v; };

__device__ __forceinline__ unsigned short f2bf(float f) {
  unsigned u = __builtin_bit_cast(unsigned, f);
  u += 0x7fffu + ((u >> 16) & 1u);
  return (unsigned short)(u >> 16);
}
__device__ __forceinline__ float bf2f(unsigned short b) {
  unsigned u = ((unsigned)b) << 16;
  return __builtin_bit_cast(float, u);
}

// ---------------- weight transpose + bf16 cast: w[b][K][128] -> wT[b][128][K]
__global__ void tcast_kernel(const float* __restrict__ w, unsigned short* __restrict__ wT,
                             int K, int total) {
  int t = blockIdx.x * blockDim.x + threadIdx.x;
  if (t >= total) return;
  int b = t / (K * 128);
  int rem = t - b * K * 128;
  int r = rem / 128;
  int c = rem - r * 128;
  wT[(size_t)b * 128 * K + (size_t)c * K + r] = f2bf(w[t]);
}

// ---------------- edge-index dtype detector: int64 => all odd int32 words are 0
__global__ void detect_kernel(const int* __restrict__ ei, int samples, int* __restrict__ flag) {
  int t = blockIdx.x * blockDim.x + threadIdx.x;
  if (t < samples && (t & 1) && ei[t] != 0) atomicOr(flag, 1);  // 1 => int32 layout
}

// ---------------- in-degree counts (int), 4 edges/thread for atomic ILP
__global__ void counti_kernel(const int* __restrict__ ei, const int* __restrict__ flag,
                              int* __restrict__ cnt, int E) {
  int base = (blockIdx.x * blockDim.x + threadIdx.x) * 4;
  int f = *flag;
#pragma unroll
  for (int j = 0; j < 4; j++) {
    int e = base + j;
    if (e < E) {
      size_t pos = (size_t)E + e;
      int t = f ? ei[pos] : ei[pos * 2];
      atomicAdd(&cnt[t], 1);
    }
  }
}

// ---------------- hierarchical exclusive scan (1024 elems / block)
__global__ __launch_bounds__(256) void scanA_kernel(const int* __restrict__ cnt,
                                                    int* __restrict__ bsums, int N) {
  int base = blockIdx.x * 1024 + threadIdx.x * 4;
  int s = 0;
#pragma unroll
  for (int j = 0; j < 4; j++) { int i = base + j; if (i < N) s += cnt[i]; }
#pragma unroll
  for (int m = 1; m < 64; m <<= 1) s += __shfl_xor(s, m, 64);
  __shared__ int ws[4];
  int lane = threadIdx.x & 63, wv = threadIdx.x >> 6;
  if (lane == 0) ws[wv] = s;
  __syncthreads();
  if (threadIdx.x == 0) bsums[blockIdx.x] = ws[0] + ws[1] + ws[2] + ws[3];
}

__global__ __launch_bounds__(256) void scanB_kernel(int* __restrict__ bsums, int NB) {
  int tid = threadIdx.x;
  int base = tid * 4;
  int v[4];
#pragma unroll
  for (int j = 0; j < 4; j++) v[j] = (base + j < NB) ? bsums[base + j] : 0;
  int s = v[0] + v[1] + v[2] + v[3];
  int lane = tid & 63, wv = tid >> 6;
  int ps = s;
#pragma unroll
  for (int d = 1; d < 64; d <<= 1) { int o = __shfl_up(ps, d, 64); if (lane >= d) ps += o; }
  __shared__ int ws[4];
  if (lane == 63) ws[wv] = ps;
  __syncthreads();
  int woff = 0;
  for (int i = 0; i < wv; i++) woff += ws[i];
  int run = woff + ps - s;  // exclusive prefix
#pragma unroll
  for (int j = 0; j < 4; j++) {
    if (base + j < NB) { int t = bsums[base + j]; bsums[base + j] = run; run += t; }
  }
}

__global__ __launch_bounds__(256) void scanC_kernel(const int* __restrict__ cnt,
                                                    const int* __restrict__ bsums,
                                                    int* __restrict__ off, int N) {
  int base = blockIdx.x * 1024 + threadIdx.x * 4;
  int v[4];
#pragma unroll
  for (int j = 0; j < 4; j++) v[j] = (base + j < N) ? cnt[base + j] : 0;
  int s = v[0] + v[1] + v[2] + v[3];
  int lane = threadIdx.x & 63, wv = threadIdx.x >> 6;
  int ps = s;
#pragma unroll
  for (int d = 1; d < 64; d <<= 1) { int o = __shfl_up(ps, d, 64); if (lane >= d) ps += o; }
  __shared__ int ws[4];
  if (lane == 63) ws[wv] = ps;
  __syncthreads();
  int woff = 0;
  for (int i = 0; i < wv; i++) woff += ws[i];
  int run = woff + ps - s + bsums[blockIdx.x];
#pragma unroll
  for (int j = 0; j < 4; j++) {
    if (base + j < N) { off[base + j] = run; run += v[j]; }
  }
}

// ---------------- CSR fill, 4 edges/thread for atomic ILP
__global__ void fill_kernel(const int* __restrict__ ei, const int* __restrict__ flag,
                            const int* __restrict__ off, int* __restrict__ cursor,
                            int* __restrict__ elist, int E) {
  int base = (blockIdx.x * blockDim.x + threadIdx.x) * 4;
  int f = *flag;
#pragma unroll
  for (int j = 0; j < 4; j++) {
    int e = base + j;
    if (e < E) {
      int s = f ? ei[e] : ei[(size_t)e * 2];
      int t = f ? ei[(size_t)E + e] : ei[((size_t)E + e) * 2];
      int p = off[t] + atomicAdd(&cursor[t], 1);
      elist[p] = s;
    }
  }
}

// ================= MLP building blocks: 128-row tile, 8 waves (512 thr) =====

template <int K, int NT>
__device__ __forceinline__ void stage_x(const float* __restrict__ in, unsigned short* xs,
                                        int row0, int N, int tid) {
  constexpr int CPR = K / 8;
  for (int c = tid; c < 128 * CPR; c += NT) {
    int r = c / CPR;
    int kc = (c % CPR) * 8;
    int g = row0 + r;
    V16 o;
    if (g < N) {
      const float4* p = (const float4*)(in + (size_t)g * K + kc);
      float4 a = p[0], b = p[1];
      o.s[0] = f2bf(a.x); o.s[1] = f2bf(a.y); o.s[2] = f2bf(a.z); o.s[3] = f2bf(a.w);
      o.s[4] = f2bf(b.x); o.s[5] = f2bf(b.y); o.s[6] = f2bf(b.z); o.s[7] = f2bf(b.w);
    } else {
      o.u.x = 0; o.u.y = 0; o.u.z = 0; o.u.w = 0;
    }
    unsigned byte = ((unsigned)(r * K + kc) * 2u) ^ ((unsigned)(r & 7) << 4);
    *(uint4*)((char*)xs + byte) = o.u;
  }
}

template <int K, int NT>
__device__ __forceinline__ void stage_w(const unsigned short* __restrict__ wT,
                                        unsigned short* wl, int tid) {
  constexpr int CPR = K / 8;
  for (int c = tid; c < 128 * CPR; c += NT) {
    int n = c / CPR;
    int kc = (c % CPR) * 8;
    uint4 v = *(const uint4*)(wT + (size_t)n * K + kc);
    unsigned byte = ((unsigned)(n * K + kc) * 2u) ^ ((unsigned)(n & 7) << 4);
    *(uint4*)((char*)wl + byte) = v;
  }
}

template <int K>
__device__ __forceinline__ void gemm_tile(const unsigned short* xs, const unsigned short* wl,
                                          int lane, int wv, f32x4 acc[8]) {
  short8 afr[K / 32];
  {
    int r = wv * 16 + (lane & 15);
    int kb = (lane >> 4) * 8;
#pragma unroll
    for (int k0 = 0; k0 < K / 32; k0++) {
      unsigned byte = ((unsigned)(r * K + k0 * 32 + kb) * 2u) ^ ((unsigned)(r & 7) << 4);
      afr[k0] = *(const short8*)((const char*)xs + byte);
    }
  }
  int cb = lane & 15;
  int kb = (lane >> 4) * 8;
#pragma unroll
  for (int n0 = 0; n0 < 8; n0++) {
    acc[n0] = (f32x4){0.f, 0.f, 0.f, 0.f};
    int n = n0 * 16 + cb;
#pragma unroll
    for (int k0 = 0; k0 < K / 32; k0++) {
      unsigned byte = ((unsigned)(n * K + k0 * 32 + kb) * 2u) ^ ((unsigned)(n & 7) << 4);
      short8 bfr = *(const short8*)((const char*)wl + byte);
      acc[n0] = __builtin_amdgcn_mfma_f32_16x16x32_bf16(afr[k0], bfr, acc[n0], 0, 0, 0);
    }
  }
}

__device__ __forceinline__ void relu_to_xs(const f32x4 acc[8], const float* __restrict__ b,
                                           unsigned short* xs, int lane, int wv) {
  int cb = lane & 15;
  int rr0 = wv * 16 + (lane >> 4) * 4;
#pragma unroll
  for (int n0 = 0; n0 < 8; n0++) {
    int col = n0 * 16 + cb;
    float bb = b[col];
#pragma unroll
    for (int j = 0; j < 4; j++) {
      float v = acc[n0][j] + bb;
      v = v > 0.f ? v : 0.f;
      int rr = rr0 + j;
      unsigned byte = ((unsigned)(rr * 128 + col) * 2u) ^ ((unsigned)(rr & 7) << 4);
      *(unsigned short*)((char*)xs + byte) = f2bf(v);
    }
  }
}

// SiLU + LayerNorm stats; leaves SiLU values in z, returns mu/rs per row j.
__device__ __forceinline__ void silu_ln(f32x4 z[8], const float* __restrict__ b, int lane,
                                        float muv[4], float rsv[4]) {
  int cb = lane & 15;
  float sum[4] = {0.f, 0.f, 0.f, 0.f}, sq[4] = {0.f, 0.f, 0.f, 0.f};
#pragma unroll
  for (int n0 = 0; n0 < 8; n0++) {
    float bb = b[n0 * 16 + cb];
#pragma unroll
    for (int j = 0; j < 4; j++) {
      float v = z[n0][j] + bb;
      float sg = v / (1.f + __expf(-v));
      z[n0][j] = sg;
      sum[j] += sg;
      sq[j] += sg * sg;
    }
  }
#pragma unroll
  for (int m = 1; m <= 8; m <<= 1) {
#pragma unroll
    for (int j = 0; j < 4; j++) {
      sum[j] += __shfl_xor(sum[j], m, 64);
      sq[j] += __shfl_xor(sq[j], m, 64);
    }
  }
#pragma unroll
  for (int j = 0; j < 4; j++) {
    float mu = sum[j] * (1.f / 128.f);
    float var = sq[j] * (1.f / 128.f) - mu * mu;
    muv[j] = mu;
    rsv[j] = rsqrtf(var + 1e-5f);
  }
}

// ---------------- single MLP: z = LN(SiLU(relu(H@W0+b0)@W1+b1)), bf16 out
__global__ __launch_bounds__(512) void mlp_kernel(
    const float* __restrict__ in, const unsigned short* __restrict__ w0T,
    const float* __restrict__ b0, const unsigned short* __restrict__ w1T,
    const float* __restrict__ b1, unsigned short* __restrict__ outB, int N) {
  __shared__ unsigned short xs[128 * 128];
  __shared__ unsigned short wl[128 * 128];
  const int tid = threadIdx.x, lane = tid & 63, wv = tid >> 6;
  const int row0 = blockIdx.x * 128;

  stage_x<128, 512>(in, xs, row0, N, tid);
  stage_w<128, 512>(w0T, wl, tid);
  __syncthreads();
  f32x4 acc[8];
  gemm_tile<128>(xs, wl, lane, wv, acc);
  __syncthreads();
  relu_to_xs(acc, b0, xs, lane, wv);
  stage_w<128, 512>(w1T, wl, tid);
  __syncthreads();
  gemm_tile<128>(xs, wl, lane, wv, acc);

  float muv[4], rsv[4];
  silu_ln(acc, b1, lane, muv, rsv);
  int cb = lane & 15;
  int rr0 = wv * 16 + (lane >> 4) * 4;
#pragma unroll
  for (int j = 0; j < 4; j++) {
    int g = row0 + rr0 + j;
    if (g >= N) continue;
#pragma unroll
    for (int n0 = 0; n0 < 8; n0++) {
      float v = (acc[n0][j] - muv[j]) * rsv[j];
      outB[(size_t)g * 128 + n0 * 16 + cb] = f2bf(v);
    }
  }
}

// ---------------- fused double MLP: x -> h0 (f32 out) -> z0 (bf16 out)
__global__ __launch_bounds__(512) void mlp2_kernel(
    const float* __restrict__ x, const unsigned short* __restrict__ w0T,
    const float* __restrict__ b0, const unsigned short* __restrict__ w1T,
    const float* __restrict__ b1, const unsigned short* __restrict__ v0T,
    const float* __restrict__ c0, const unsigned short* __restrict__ v1T,
    const float* __restrict__ c1, float* __restrict__ h0,
    unsigned short* __restrict__ z0, int N) {
  __shared__ unsigned short xs[128 * 128];
  __shared__ unsigned short wl[128 * 128];
  const int tid = threadIdx.x, lane = tid & 63, wv = tid >> 6;
  const int row0 = blockIdx.x * 128;
  const int cb = lane & 15;
  const int rr0 = wv * 16 + (lane >> 4) * 4;

  // --- MLP A (initial embedding, K=64 input)
  stage_x<64, 512>(x, xs, row0, N, tid);
  stage_w<64, 512>(w0T, wl, tid);
  __syncthreads();
  f32x4 acc[8];
  gemm_tile<64>(xs, wl, lane, wv, acc);
  __syncthreads();
  relu_to_xs(acc, b0, xs, lane, wv);
  stage_w<128, 512>(w1T, wl, tid);
  __syncthreads();
  gemm_tile<128>(xs, wl, lane, wv, acc);
  __syncthreads();  // everyone done reading xs/wl before epilogue-write + restage

  float muv[4], rsv[4];
  silu_ln(acc, b1, lane, muv, rsv);
  // h0: write f32 to global, bf16 back into xs as next MLP's input
#pragma unroll
  for (int j = 0; j < 4; j++) {
    int g = row0 + rr0 + j;
    int rr = rr0 + j;
#pragma unroll
    for (int n0 = 0; n0 < 8; n0++) {
      float v = (acc[n0][j] - muv[j]) * rsv[j];
      int col = n0 * 16 + cb;
      if (g < N) h0[(size_t)g * 128 + col] = v;
      unsigned byte = ((unsigned)(rr * 128 + col) * 2u) ^ ((unsigned)(rr & 7) << 4);
      *(unsigned short*)((char*)xs + byte) = f2bf(v);
    }
  }
  stage_w<128, 512>(v0T, wl, tid);
  __syncthreads();

  // --- MLP B (layer 0)
  gemm_tile<128>(xs, wl, lane, wv, acc);
  __syncthreads();
  relu_to_xs(acc, c0, xs, lane, wv);
  stage_w<128, 512>(v1T, wl, tid);
  __syncthreads();
  gemm_tile<128>(xs, wl, lane, wv, acc);

  silu_ln(acc, c1, lane, muv, rsv);
#pragma unroll
  for (int j = 0; j < 4; j++) {
    int g = row0 + rr0 + j;
    if (g >= N) continue;
#pragma unroll
    for (int n0 = 0; n0 < 8; n0++) {
      float v = (acc[n0][j] - muv[j]) * rsv[j];
      z0[(size_t)g * 128 + n0 * 16 + cb] = f2bf(v);
    }
  }
}

// ---------------- gather + residual: h[n] += mean_{e in CSR[n]} z[src[e]]
// 16 lanes per node, 8 cols each; unroll-2 for load ILP.
__global__ __launch_bounds__(256) void gather_kernel(
    const unsigned short* __restrict__ z, const int* __restrict__ elist,
    const int* __restrict__ off, const int* __restrict__ cnt,
    float* __restrict__ h, int N) {
  int t = blockIdx.x * 256 + threadIdx.x;
  int g = t >> 4;
  if (g >= N) return;
  int c = (t & 15) * 8;
  int o = off[g];
  int n = cnt[g];
  float acc[8] = {0.f, 0.f, 0.f, 0.f, 0.f, 0.f, 0.f, 0.f};
  int i = 0;
  for (; i + 2 <= n; i += 2) {
    int s0 = elist[o + i];
    int s1 = elist[o + i + 1];
    V16 v0, v1;
    v0.u = *(const uint4*)(z + (size_t)s0 * 128 + c);
    v1.u = *(const uint4*)(z + (size_t)s1 * 128 + c);
#pragma unroll
    for (int j = 0; j < 8; j++) acc[j] += bf2f(v0.s[j]) + bf2f(v1.s[j]);
  }
  if (i < n) {
    int s0 = elist[o + i];
    V16 v0;
    v0.u = *(const uint4*)(z + (size_t)s0 * 128 + c);
#pragma unroll
    for (int j = 0; j < 8; j++) acc[j] += bf2f(v0.s[j]);
  }
  float inv = n > 0 ? 1.f / (float)n : 0.f;
  float* hp = h + (size_t)g * 128 + c;
  float4 h0 = *(const float4*)hp, h1 = *(const float4*)(hp + 4);
  h0.x += acc[0] * inv; h0.y += acc[1] * inv; h0.z += acc[2] * inv; h0.w += acc[3] * inv;
  h1.x += acc[4] * inv; h1.y += acc[5] * inv; h1.z += acc[6] * inv; h1.w += acc[7] * inv;
  *(float4*)hp = h0;
  *(float4*)(hp + 4) = h1;
}

extern "C" void kernel_launch(void* const* d_in, const int* in_sizes, int n_in,
                              void* d_out, int out_size, void* d_ws, size_t ws_size,
                              hipStream_t stream) {
  const float* x = (const float*)d_in[0];
  const int* ei = (const int*)d_in[1];
  const float* ie_w0 = (const float*)d_in[2];
  const float* ie_b0 = (const float*)d_in[3];
  const float* ie_w1 = (const float*)d_in[4];
  const float* ie_b1 = (const float*)d_in[5];
  const float* lw0 = (const float*)d_in[6];
  const float* lb0 = (const float*)d_in[7];
  const float* lw1 = (const float*)d_in[8];
  const float* lb1 = (const float*)d_in[9];
  const int N = in_sizes[0] / 64;
  const int E = in_sizes[1] / 2;
  float* h = (float*)d_out;

  char* ws = (char*)d_ws;
  size_t off_b = 0;
  auto carve = [&](size_t bytes) { void* p = ws + off_b; off_b = (off_b + bytes + 255) & ~(size_t)255; return p; };
  unsigned short* zbuf = (unsigned short*)carve((size_t)N * 128 * 2);
  int* elist = (int*)carve((size_t)E * 4);
  int* offs = (int*)carve((size_t)N * 4);
  int* flag = (int*)carve(256);                  // flag..cursor zeroed in one memset
  int* cnti = (int*)carve((size_t)N * 4);
  int* cursor = (int*)carve((size_t)N * 4);
  size_t zspan = (char*)(cursor + N) - (char*)flag;
  int* bsums = (int*)carve(((size_t)(N + 1023) / 1024) * 4 + 256);
  unsigned short* w0T_ie = (unsigned short*)carve(128 * 64 * 2);
  unsigned short* w1T_ie = (unsigned short*)carve(128 * 128 * 2);
  unsigned short* w0T_l = (unsigned short*)carve(3 * 128 * 128 * 2);
  unsigned short* w1T_l = (unsigned short*)carve(3 * 128 * 128 * 2);

  const int NB = (N + 1023) / 1024;

  // dtype detect (int32 vs int64 edge_index), weight prep
  hipMemsetAsync(flag, 0, zspan, stream);
  int samples = 2 * E < 8192 ? 2 * E : 8192;
  detect_kernel<<<(samples + 255) / 256, 256, 0, stream>>>(ei, samples, flag);
  tcast_kernel<<<(64 * 128 + 255) / 256, 256, 0, stream>>>(ie_w0, w0T_ie, 64, 64 * 128);
  tcast_kernel<<<(128 * 128 + 255) / 256, 256, 0, stream>>>(ie_w1, w1T_ie, 128, 128 * 128);
  tcast_kernel<<<(3 * 128 * 128 + 255) / 256, 256, 0, stream>>>(lw0, w0T_l, 128, 3 * 128 * 128);
  tcast_kernel<<<(3 * 128 * 128 + 255) / 256, 256, 0, stream>>>(lw1, w1T_l, 128, 3 * 128 * 128);

  // CSR build: counts -> exclusive scan -> bucket fill
  counti_kernel<<<(E / 4 + 256) / 256, 256, 0, stream>>>(ei, flag, cnti, E);
  scanA_kernel<<<NB, 256, 0, stream>>>(cnti, bsums, N);
  scanB_kernel<<<1, 256, 0, stream>>>(bsums, NB);
  scanC_kernel<<<NB, 256, 0, stream>>>(cnti, bsums, offs, N);
  fill_kernel<<<(E / 4 + 256) / 256, 256, 0, stream>>>(ei, flag, offs, cursor, elist, E);

  // fused: h0 = LN(SiLU(relu(x@W0+b0)@W1+b1)); z0 = MLP_layer0(h0)
  mlp2_kernel<<<(N + 127) / 128, 512, 0, stream>>>(
      x, w0T_ie, ie_b0, w1T_ie, ie_b1,
      w0T_l, lb0, w1T_l, lb1, h, zbuf, N);
  gather_kernel<<<((size_t)N * 16 + 255) / 256, 256, 0, stream>>>(
      zbuf, elist, offs, cnti, h, N);

  for (int l = 1; l < 3; l++) {
    mlp_kernel<<<(N + 127) / 128, 512, 0, stream>>>(
        h, w0T_l + (size_t)l * 128 * 128, lb0 + (size_t)l * 128,
        w1T_l + (size_t)l * 128 * 128, lb1 + (size_t)l * 128, zbuf, N);
    gather_kernel<<<((size_t)N * 16 + 255) / 256, 256, 0, stream>>>(
        zbuf, elist, offs, cnti, h, N);
  }
}